// Round 6
// baseline (653.978 us; speedup 1.0000x reference)
//
#include <hip/hip_runtime.h>
#include <hip/hip_bf16.h>
#include <stdint.h>

typedef __bf16 bf16_t;
typedef __bf16 bf16x8 __attribute__((ext_vector_type(8)));
typedef float f32x4 __attribute__((ext_vector_type(4)));
typedef float floatv4 __attribute__((ext_vector_type(4)));

static __device__ __forceinline__ float bflo(unsigned int p){ return __uint_as_float(p << 16); }
static __device__ __forceinline__ float bfhi(unsigned int p){ return __uint_as_float(p & 0xffff0000u); }
static __device__ __forceinline__ unsigned int pack2(float lo, float hi){
  union { bf16_t h[2]; unsigned int u; } o;
  o.h[0] = (bf16_t)lo; o.h[1] = (bf16_t)hi;
  return o.u;
}
// packed edge: bits[16:0]=col (<131072), bits[31:17]=weight f32 bits[30:16] (sign implicit)
static __device__ __forceinline__ unsigned packEdge(int col, float w_pos){
  unsigned b = __float_as_uint(w_pos) + 0x8000u;       // round-to-nearest on bit16
  return ((b >> 16) << 17) | (unsigned)col;
}
static __device__ __forceinline__ float edgeWpos(unsigned u){   // raw (positive) weight
  return __uint_as_float((u >> 17) << 16);
}
static __device__ __forceinline__ float edgeWneg(unsigned u){   // normalized (negative) weight
  return __uint_as_float(0x80000000u | ((u >> 17) << 16));
}

constexpr int NN = 100000;
constexpr int NE = 1600000;
constexpr int NB_G = (NN + 127)/128;   // 782
constexpr int NB_E = (NE + 255)/256;   // 6250
// Sliced bf16 feature layout: addr(node,f) = base + ((f>>4)*NN + node)*32B + (f&15)*2
// 8 slices x 3.2MB; slice s gathered only by blocks with bid&7==s (XCD-pinned L2 window).

// ---------------- CSR build ----------------
__global__ void k_count(const int* __restrict__ row, int* __restrict__ cnt,
                        int* __restrict__ pos, int e){
  int i = blockIdx.x*256 + threadIdx.x;
  if (i < e) pos[i] = atomicAdd(&cnt[row[i]], 1);
}

__global__ void k_scan1(const int* __restrict__ cnt, int* __restrict__ tmp,
                        int* __restrict__ bsum, int n){
  __shared__ int s[256];
  int i = blockIdx.x*256 + threadIdx.x;
  s[threadIdx.x] = (i < n) ? cnt[i] : 0;
  __syncthreads();
  for (int off = 1; off < 256; off <<= 1){
    int t = (threadIdx.x >= off) ? s[threadIdx.x - off] : 0;
    __syncthreads();
    s[threadIdx.x] += t;
    __syncthreads();
  }
  if (i < n) tmp[i] = s[threadIdx.x];
  if (threadIdx.x == 255) bsum[blockIdx.x] = s[255];
}

__global__ void k_scan2(int* bsum, int nb){
  if (threadIdx.x == 0 && blockIdx.x == 0){
    int run = 0;
    for (int b = 0; b < nb; ++b){ int t = bsum[b]; bsum[b] = run; run += t; }
  }
}

__global__ void k_scan3(const int* __restrict__ tmp, const int* __restrict__ bsum,
                        int* __restrict__ rowptr, int n){
  int i = blockIdx.x*256 + threadIdx.x;
  if (i < n) rowptr[i+1] = tmp[i] + bsum[blockIdx.x];
  if (i == 0) rowptr[0] = 0;
}

__global__ void k_fill2(const int* __restrict__ row, const int* __restrict__ col,
                        const float* __restrict__ w, const int* __restrict__ rowptr,
                        const int* __restrict__ pos, unsigned* __restrict__ ec, int e){
  int i = blockIdx.x*256 + threadIdx.x;
  if (i < e){
    int r = row[i];
    int p = rowptr[r] + pos[i];
    ec[p] = packEdge(col[i], w[i]);    // raw positive weight
  }
}

__global__ __launch_bounds__(256) void k_deg2(const unsigned* __restrict__ ec,
                                              const int* __restrict__ rowptr,
                                              float* __restrict__ dinv, int n){
  int node = blockIdx.x*4 + (threadIdx.x >> 6);
  if (node >= n) return;
  int lane = threadIdx.x & 63;
  int e0 = rowptr[node], e1 = rowptr[node+1];
  float s = 0.f;
  for (int e = e0 + lane; e < e1; e += 64) s += edgeWpos(ec[e]);
  #pragma unroll
  for (int off = 32; off > 0; off >>= 1) s += __shfl_xor(s, off, 64);
  if (lane == 0) dinv[node] = (s > 0.f) ? rsqrtf(s) : 0.f;
}

__global__ __launch_bounds__(256) void k_norm(unsigned* __restrict__ ec,
                                              const int* __restrict__ rowptr,
                                              const float* __restrict__ dinv, int n){
  int node = blockIdx.x*4 + (threadIdx.x >> 6);
  if (node >= n) return;
  int lane = threadIdx.x & 63;
  int e0 = rowptr[node], e1 = rowptr[node+1];
  float dr = dinv[node];
  for (int e = e0 + lane; e < e1; e += 64){
    unsigned u = ec[e];
    int c = u & 0x1FFFF;
    float wn = dr * edgeWpos(u) * dinv[c];    // positive; spmm applies the minus sign
    ec[e] = packEdge(c, wn);
  }
}

__global__ void k_transw_all(const float* __restrict__ W1, const float* __restrict__ c1W,
                             const float* __restrict__ c2W, bf16_t* __restrict__ Wt1,
                             bf16_t* __restrict__ Wtc1, bf16_t* __restrict__ Wtc2){
  int idx = blockIdx.x*256 + threadIdx.x;   // 8*16384 total
  const float* src; bf16_t* dst; int local;
  if (idx < 2*16384)      { src = W1;  dst = Wt1;  local = idx; }
  else if (idx < 5*16384) { src = c1W; dst = Wtc1; local = idx - 2*16384; }
  else                    { src = c2W; dst = Wtc2; local = idx - 5*16384; }
  int c = local >> 14, r = (local >> 7) & 127, j = local & 127;
  dst[(c << 14) + (j << 7) + r] = (bf16_t)src[local];
}

// ---------------- GEMM1: A_sliced = relu(x @ W1 + b1), x f32 row-major K=256 ------
__global__ __launch_bounds__(256) void k_gemm1(
    const float* __restrict__ x, const bf16_t* __restrict__ Wt, const float* __restrict__ bias,
    bf16_t* __restrict__ out, int M)
{
  __shared__ bf16_t As[128][40];
  const int tid = threadIdx.x;
  const int wave = tid >> 6, lane = tid & 63;
  const int wm = wave >> 1, wn = wave & 1;
  const int l15 = lane & 15, lq = lane >> 4;
  const int blockRow = blockIdx.x * 128;

  f32x4 acc[4][4];
  #pragma unroll
  for (int a = 0; a < 4; ++a)
    #pragma unroll
    for (int b = 0; b < 4; ++b) acc[a][b] = f32x4{0.f,0.f,0.f,0.f};

  const int srow = tid >> 1;
  const int scol = (tid & 1) * 16;
  const int grow = blockRow + srow;

  #pragma unroll
  for (int chunk = 0; chunk < 2; ++chunk){
    #pragma unroll
    for (int k4 = 0; k4 < 4; ++k4){
      const int kk = k4 * 32;
      {
        union { bf16_t h[16]; uint4 q[2]; } u;
        if (grow < M){
          const float* p = x + (size_t)grow*256 + chunk*128 + kk + scol;
          floatv4 vv[4];
          #pragma unroll
          for (int j = 0; j < 4; ++j) vv[j] = *(const floatv4*)(p + j*4);
          #pragma unroll
          for (int j = 0; j < 16; ++j) u.h[j] = (bf16_t)vv[j>>2][j&3];
        } else {
          u.q[0] = make_uint4(0,0,0,0);
          u.q[1] = make_uint4(0,0,0,0);
        }
        *(uint4*)&As[srow][scol]     = u.q[0];
        *(uint4*)&As[srow][scol + 8] = u.q[1];
      }
      __syncthreads();
      bf16x8 af[4], bfr[4];
      #pragma unroll
      for (int fm = 0; fm < 4; ++fm)
        af[fm] = *(const bf16x8*)&As[wm*64 + fm*16 + l15][lq*8];
      #pragma unroll
      for (int fn = 0; fn < 4; ++fn){
        int colg = wn*64 + fn*16 + l15;
        bfr[fn] = *(const bf16x8*)&Wt[((size_t)((chunk << 7) + colg) << 7) + kk + lq*8];
      }
      #pragma unroll
      for (int fm = 0; fm < 4; ++fm)
        #pragma unroll
        for (int fn = 0; fn < 4; ++fn)
          acc[fm][fn] = __builtin_amdgcn_mfma_f32_16x16x32_bf16(af[fm], bfr[fn], acc[fm][fn], 0, 0, 0);
      __syncthreads();
    }
  }
  #pragma unroll
  for (int fm = 0; fm < 4; ++fm){
    #pragma unroll
    for (int j = 0; j < 4; ++j){
      int growo = blockRow + wm*64 + fm*16 + lq*4 + j;
      if (growo < M){
        #pragma unroll
        for (int fn = 0; fn < 4; ++fn){
          float v = fmaxf(acc[fm][fn][j] + bias[wn*64 + fn*16 + l15], 0.f);
          char* po = (char*)out + ((size_t)((wn*4 + fn)*NN + growo))*32 + l15*2;
          *(bf16_t*)po = (bf16_t)v;
        }
      }
    }
  }
}

// ---------------- conv GEMM, barrier-free, sliced A in / sliced out ----------------
// OUT = relu([A0|A1|A2] @ Wt^T + b). Per-wave af reads use full 32B cells:
// lanes (lq=0,l15) + (lq=1,l15) read the two 16B halves of the same cell.
__global__ __launch_bounds__(256) void k_gemm_nb(
    const bf16_t* __restrict__ a0, const bf16_t* __restrict__ a1, const bf16_t* __restrict__ a2,
    const bf16_t* __restrict__ Wt, const float* __restrict__ bias,
    bf16_t* __restrict__ out, int M)
{
  const int tid = threadIdx.x;
  const int wave = tid >> 6, lane = tid & 63;
  const int wm = wave >> 1, wn = wave & 1;
  const int l15 = lane & 15, lq = lane >> 4;
  const int blockRow = blockIdx.x * 128;
  const int arow = blockRow + wm*64 + l15;   // + fm*16
  // last block reads A rows [100000,100096): spills into the adjacent ws buffer
  // (allocated, value-irrelevant — those acc rows are never stored).

  f32x4 acc[4][4];
  #pragma unroll
  for (int a = 0; a < 4; ++a)
    #pragma unroll
    for (int b = 0; b < 4; ++b) acc[a][b] = f32x4{0.f,0.f,0.f,0.f};

  #pragma unroll
  for (int chunk = 0; chunk < 3; ++chunk){
    const bf16_t* src = (chunk == 0) ? a0 : ((chunk == 1) ? a1 : a2);
    #pragma unroll
    for (int k4 = 0; k4 < 4; ++k4){
      bf16x8 af[4], bfr[4];
      const int slice = k4*2 + (lq >> 1);
      const int half  = (lq & 1) * 16;
      #pragma unroll
      for (int fm = 0; fm < 4; ++fm)
        af[fm] = *(const bf16x8*)((const char*)src + ((size_t)(slice*NN + arow + fm*16))*32 + half);
      const int kk = k4*32 + lq*8;
      #pragma unroll
      for (int fn = 0; fn < 4; ++fn)
        bfr[fn] = *(const bf16x8*)(Wt + ((size_t)((chunk << 7) + wn*64 + fn*16 + l15) << 7) + kk);
      #pragma unroll
      for (int fm = 0; fm < 4; ++fm)
        #pragma unroll
        for (int fn = 0; fn < 4; ++fn)
          acc[fm][fn] = __builtin_amdgcn_mfma_f32_16x16x32_bf16(af[fm], bfr[fn], acc[fm][fn], 0, 0, 0);
    }
  }
  #pragma unroll
  for (int fm = 0; fm < 4; ++fm){
    #pragma unroll
    for (int j = 0; j < 4; ++j){
      int growo = blockRow + wm*64 + fm*16 + lq*4 + j;
      if (growo < M){
        #pragma unroll
        for (int fn = 0; fn < 4; ++fn){
          float v = fmaxf(acc[fm][fn][j] + bias[wn*64 + fn*16 + l15], 0.f);
          char* po = (char*)out + ((size_t)((wn*4 + fn)*NN + growo))*32 + l15*2;
          *(bf16_t*)po = (bf16_t)v;
        }
      }
    }
  }
}

// ---------------- SpMM sliced (v2): cached edge loads, packed 4B edges ------------
// out[i] = alpha * sum_e (-wn[e])*V[col[e]]  (- sub[i]); slice = bid&7 -> XCD-pinned
// 3.2MB V-slice. 32 nodes/block, 8 lanes/node (4B each of the 32B slice cell).
__global__ __launch_bounds__(256) void k_spmm_s(
    const int* __restrict__ rowptr, const unsigned* __restrict__ ec,
    const bf16_t* __restrict__ V, const bf16_t* __restrict__ sub, float alpha,
    bf16_t* __restrict__ out, int n)
{
  const int slice = blockIdx.x & 7;
  const int chunk = blockIdx.x >> 3;
  const int tid = threadIdx.x;
  const int node = chunk*32 + (tid >> 3);
  const int sw = tid & 7;
  if (node >= n) return;

  const char* Vb = (const char*)V + (size_t)slice*NN*32 + sw*4;
  int e = rowptr[node];
  const int e1 = rowptr[node+1];
  float a0 = 0.f, a1 = 0.f;

  for (; e + 4 <= e1; e += 4){
    unsigned u0 = ec[e], u1 = ec[e+1], u2 = ec[e+2], u3 = ec[e+3];
    unsigned p0 = *(const unsigned*)(Vb + ((size_t)(u0 & 0x1FFFF)) * 32);
    unsigned p1 = *(const unsigned*)(Vb + ((size_t)(u1 & 0x1FFFF)) * 32);
    unsigned p2 = *(const unsigned*)(Vb + ((size_t)(u2 & 0x1FFFF)) * 32);
    unsigned p3 = *(const unsigned*)(Vb + ((size_t)(u3 & 0x1FFFF)) * 32);
    float w0 = edgeWneg(u0), w1 = edgeWneg(u1);
    float w2 = edgeWneg(u2), w3 = edgeWneg(u3);
    a0 += w0*bflo(p0); a1 += w0*bfhi(p0);
    a0 += w1*bflo(p1); a1 += w1*bfhi(p1);
    a0 += w2*bflo(p2); a1 += w2*bfhi(p2);
    a0 += w3*bflo(p3); a1 += w3*bfhi(p3);
  }
  for (; e < e1; ++e){
    unsigned u = ec[e];
    unsigned p = *(const unsigned*)(Vb + ((size_t)(u & 0x1FFFF)) * 32);
    float w = edgeWneg(u);
    a0 += w*bflo(p); a1 += w*bfhi(p);
  }

  float r0 = alpha*a0, r1 = alpha*a1;
  const size_t cell = ((size_t)(slice*NN + node))*32 + sw*4;
  if (sub){
    unsigned sv = *(const unsigned*)((const char*)sub + cell);
    r0 -= bflo(sv); r1 -= bfhi(sv);
  }
  *(unsigned*)((char*)out + cell) = pack2(r0, r1);
}

// ---------------- head: logits = h@W2 + b2 ; softmax over 2 classes (sliced h) ----
__global__ __launch_bounds__(256) void k_head(
    const bf16_t* __restrict__ h, const float* __restrict__ W2, const float* __restrict__ b2,
    float* __restrict__ out, int n)
{
  int node = blockIdx.x*4 + (threadIdx.x >> 6);
  if (node >= n) return;
  int lane = threadIdx.x & 63;
  const char* hb = (const char*)h + ((size_t)((lane >> 3)*NN + node))*32 + (lane & 7)*4;
  unsigned p = *(const unsigned*)hb;
  float h0 = bflo(p), h1 = bfhi(p);
  floatv4 w = *(const floatv4*)(W2 + lane*4);
  float p0 = h0*w[0] + h1*w[2];
  float p1 = h0*w[1] + h1*w[3];
  #pragma unroll
  for (int s = 32; s > 0; s >>= 1){
    p0 += __shfl_xor(p0, s, 64);
    p1 += __shfl_xor(p1, s, 64);
  }
  if (lane == 0){
    float l0 = p0 + b2[0], l1 = p1 + b2[1];
    float m = fmaxf(l0, l1);
    float e0 = __expf(l0 - m), e1 = __expf(l1 - m);
    float inv = 1.f / (e0 + e1);
    out[(size_t)node*2]     = e0 * inv;
    out[(size_t)node*2 + 1] = e1 * inv;
  }
}

// ---------------- launch ----------------

extern "C" void kernel_launch(void* const* d_in, const int* in_sizes, int n_in,
                              void* d_out, int out_size, void* d_ws, size_t ws_size,
                              hipStream_t stream)
{
  const float* x   = (const float*)d_in[0];
  const int*   ei  = (const int*)d_in[1];
  const float* ew  = (const float*)d_in[2];
  const float* W1  = (const float*)d_in[3];
  const float* b1  = (const float*)d_in[4];
  const float* c1W = (const float*)d_in[5];
  const float* c1b = (const float*)d_in[6];
  const float* c2W = (const float*)d_in[7];
  const float* c2b = (const float*)d_in[8];
  const float* W2  = (const float*)d_in[9];
  const float* b2  = (const float*)d_in[10];
  float* out = (float*)d_out;

  const int n = NN, e = NE;
  const int* row = ei;
  const int* col = ei + e;

  char* ws = (char*)d_ws;
  size_t off = 0;
  auto carve = [&](size_t bytes)->void*{
    void* p = ws + off;
    off += (bytes + 255) & ~(size_t)255;
    return p;
  };
  bf16_t* A    = (bf16_t*)carve((size_t)n*128*2);
  bf16_t* B    = (bf16_t*)carve((size_t)n*128*2);
  bf16_t* C    = (bf16_t*)carve((size_t)n*128*2);
  bf16_t* D    = (bf16_t*)carve((size_t)n*128*2);
  float*  dinv = (float*)carve((size_t)n*4);
  int*    cnt  = (int*)carve((size_t)n*4);
  int*    rowptr = (int*)carve((size_t)(n+1)*4);
  int*    bsum = (int*)carve(512*4);
  unsigned* ec = (unsigned*)carve((size_t)e*4);
  bf16_t* Wt1  = (bf16_t*)carve(2*128*128*2);
  bf16_t* Wtc1 = (bf16_t*)carve(3*128*128*2);
  bf16_t* Wtc2 = (bf16_t*)carve(3*128*128*2);
  // aliases (lifetimes end before their hosts are first written):
  int* pos = (int*)B;     // used k_count..k_fill2; B first written by spmm later
  int* tmp = (int*)C;     // used scan1..scan3; C first written by spmm later
  (void)ws_size; (void)in_sizes; (void)n_in; (void)out_size;

  const int NB_N = (n + 255)/256;   // 391
  const int NB_W = (n + 3)/4;       // 25000
  const int NB_S = ((n + 31)/32)*8; // 25000 (8 slices x 3125 chunks)

  hipMemsetAsync(cnt, 0, (size_t)n*4, stream);
  k_transw_all<<<(8*16384+255)/256,256,0,stream>>>(W1, c1W, c2W, Wt1, Wtc1, Wtc2);
  k_count<<<NB_E,256,0,stream>>>(row, cnt, pos, e);
  k_scan1<<<NB_N,256,0,stream>>>(cnt, tmp, bsum, n);
  k_scan2<<<1,64,0,stream>>>(bsum, NB_N);
  k_scan3<<<NB_N,256,0,stream>>>(tmp, bsum, rowptr, n);
  k_fill2<<<NB_E,256,0,stream>>>(row, col, ew, rowptr, pos, ec, e);
  k_deg2<<<NB_W,256,0,stream>>>(ec, rowptr, dinv, n);
  k_norm<<<NB_W,256,0,stream>>>(ec, rowptr, dinv, n);

  // h0 = relu(x @ W1 + b1) -> A (sliced)
  k_gemm1<<<NB_G,256,0,stream>>>(x, Wt1, b1, A, n);
  // conv1: Tx1 = Lx(h0) -> B ; Tx2 = 2*Lx(Tx1) - h0 -> C
  k_spmm_s<<<NB_S,256,0,stream>>>(rowptr, ec, A, nullptr, 1.f, B, n);
  k_spmm_s<<<NB_S,256,0,stream>>>(rowptr, ec, B, A, 2.f, C, n);
  k_gemm_nb<<<NB_G,256,0,stream>>>(A, B, C, Wtc1, c1b, D, n);
  // conv2
  k_spmm_s<<<NB_S,256,0,stream>>>(rowptr, ec, D, nullptr, 1.f, B, n);
  k_spmm_s<<<NB_S,256,0,stream>>>(rowptr, ec, B, D, 2.f, C, n);
  k_gemm_nb<<<NB_G,256,0,stream>>>(D, B, C, Wtc2, c2b, A, n);
  // head
  k_head<<<NB_W,256,0,stream>>>(A, W2, b2, out, n);
}

// Round 7
// 478.646 us; speedup vs baseline: 1.3663x; 1.3663x over previous
//
#include <hip/hip_runtime.h>
#include <hip/hip_bf16.h>
#include <stdint.h>

typedef __bf16 bf16_t;
typedef __bf16 bf16x8 __attribute__((ext_vector_type(8)));
typedef float f32x4 __attribute__((ext_vector_type(4)));
typedef float floatv4 __attribute__((ext_vector_type(4)));

static __device__ __forceinline__ float bflo(unsigned int p){ return __uint_as_float(p << 16); }
static __device__ __forceinline__ float bfhi(unsigned int p){ return __uint_as_float(p & 0xffff0000u); }
static __device__ __forceinline__ unsigned int pack2(float lo, float hi){
  union { bf16_t h[2]; unsigned int u; } o;
  o.h[0] = (bf16_t)lo; o.h[1] = (bf16_t)hi;
  return o.u;
}
// packed edge: bits[16:0]=col (<131072), bits[31:17]=weight f32 bits[30:16] (sign implicit)
static __device__ __forceinline__ unsigned packEdge(int col, float w_pos){
  unsigned b = __float_as_uint(w_pos) + 0x8000u;       // round-to-nearest on bit16
  return ((b >> 16) << 17) | (unsigned)col;
}
static __device__ __forceinline__ float edgeWpos(unsigned u){   // positive weight
  return __uint_as_float((u >> 17) << 16);
}
static __device__ __forceinline__ float edgeWneg(unsigned u){   // negated weight
  return __uint_as_float(0x80000000u | ((u >> 17) << 16));
}

constexpr int NN = 100000;
constexpr int NE = 1600000;
constexpr int NB_G = (NN + 127)/128;     // 782 gemm tile blocks
constexpr int NBIN = (NN + 127)/128;     // 782 row-bins (row>>7)
constexpr int EPB  = 4096;               // edges per bin-pass block
constexpr int NBB  = (NE + EPB - 1)/EPB; // 391
constexpr int MAXBE = 3072;              // max edges per bin (E[bin]=2048, sigma~45)

// ---------------- binned CSR build (replaces 1.6M-atomic count path) ----------------
// pass A: per-block LDS histogram over bins; one global atomic per (block,bin)
__global__ __launch_bounds__(256) void k_binA(const int* __restrict__ row,
                                              int* __restrict__ bincnt,
                                              int* __restrict__ blockbase){
  __shared__ int h[NBIN];
  for (int b = threadIdx.x; b < NBIN; b += 256) h[b] = 0;
  __syncthreads();
  int base = blockIdx.x * EPB;
  for (int k = 0; k < EPB; k += 256){
    int i = base + k + threadIdx.x;
    if (i < NE) atomicAdd(&h[row[i] >> 7], 1);
  }
  __syncthreads();
  for (int b = threadIdx.x; b < NBIN; b += 256){
    int c = h[b];
    blockbase[blockIdx.x * NBIN + b] = c ? atomicAdd(&bincnt[b], c) : 0;
  }
}

// exclusive scan of 782 bin counts (one block)
__global__ __launch_bounds__(256) void k_scanbins(const int* __restrict__ bincnt,
                                                  int* __restrict__ binptr,
                                                  int* __restrict__ rowptr){
  __shared__ int s[256];
  int t = threadIdx.x;
  int b0 = t*4;
  int c[4]; int tot = 0;
  #pragma unroll
  for (int j = 0; j < 4; ++j){
    int b = b0 + j;
    c[j] = (b < NBIN) ? bincnt[b] : 0;
    tot += c[j];
  }
  s[t] = tot;
  __syncthreads();
  for (int off = 1; off < 256; off <<= 1){
    int v = (t >= off) ? s[t - off] : 0;
    __syncthreads();
    s[t] += v;
    __syncthreads();
  }
  int ex = s[t] - tot;
  #pragma unroll
  for (int j = 0; j < 4; ++j){
    int b = b0 + j;
    if (b < NBIN) binptr[b] = ex;
    ex += c[j];
  }
  if (t == 255){ binptr[NBIN] = ex; rowptr[NN] = ex; }   // both = NE
}

// pass B: re-rank in LDS, scatter edges to bin-grouped temp (rowlocal packed in x)
__global__ __launch_bounds__(256) void k_binB(const int* __restrict__ row,
                                              const int* __restrict__ col,
                                              const float* __restrict__ w,
                                              const int* __restrict__ binptr,
                                              const int* __restrict__ blockbase,
                                              int2* __restrict__ temp){
  __shared__ int h[NBIN];
  for (int b = threadIdx.x; b < NBIN; b += 256) h[b] = 0;
  __syncthreads();
  int base = blockIdx.x * EPB;
  for (int k = 0; k < EPB; k += 256){
    int i = base + k + threadIdx.x;
    if (i < NE){
      int r = row[i];
      int b = r >> 7;
      int rank = atomicAdd(&h[b], 1);
      int pos = binptr[b] + blockbase[blockIdx.x * NBIN + b] + rank;
      temp[pos] = make_int2(col[i] | ((r & 127) << 17), __float_as_int(w[i]));
    }
  }
}

// pass C: one block per bin; LDS row-sort, emit packed ec + rowptr + deg/dinv
__global__ __launch_bounds__(256) void k_binC(const int2* __restrict__ temp,
                                              const int* __restrict__ binptr,
                                              unsigned* __restrict__ ec,
                                              int* __restrict__ rowptr,
                                              float* __restrict__ dinv, int n){
  __shared__ int2 sbuf[MAXBE];
  __shared__ int cnt[128];
  __shared__ int scan[128];
  __shared__ int estart[128];
  const int b = blockIdx.x;
  const int e0 = binptr[b];
  int nb = binptr[b+1] - e0; if (nb > MAXBE) nb = MAXBE;
  const int t = threadIdx.x;
  if (t < 128) cnt[t] = 0;
  __syncthreads();
  // phase 1: count rows
  for (int k = t; k < nb; k += 256)
    atomicAdd(&cnt[(temp[e0+k].x >> 17) & 127], 1);
  __syncthreads();
  // inclusive scan over 128, then exclusive starts
  if (t < 128) scan[t] = cnt[t];
  __syncthreads();
  for (int off = 1; off < 128; off <<= 1){
    int v = (t < 128 && t >= off) ? scan[t - off] : 0;
    __syncthreads();
    if (t < 128) scan[t] += v;
    __syncthreads();
  }
  if (t < 128){ estart[t] = scan[t] - cnt[t]; cnt[t] = 0; }
  __syncthreads();
  // phase 2: re-rank and scatter into sorted LDS buffer
  for (int k = t; k < nb; k += 256){
    int2 q = temp[e0+k];
    int rl = (q.x >> 17) & 127;
    int rank = atomicAdd(&cnt[rl], 1);
    sbuf[estart[rl] + rank] = q;
  }
  __syncthreads();
  // emit packed edges (coalesced), rowptr, deg/dinv
  for (int k = t; k < nb; k += 256){
    int2 q = sbuf[k];
    ec[e0 + k] = packEdge(q.x & 0x1FFFF, __int_as_float(q.y));
  }
  if (t < 128){
    int gid = b*128 + t;
    if (gid < n){
      rowptr[gid] = e0 + estart[t];
      float s = 0.f;
      int s0 = estart[t], c = cnt[t];
      for (int j = 0; j < c; ++j) s += __int_as_float(sbuf[s0+j].y);
      dinv[gid] = (s > 0.f) ? rsqrtf(s) : 0.f;
    }
  }
}

// normalize in place: w <- dinv[r]*w*dinv[c] (kept positive; spmm applies the sign)
__global__ __launch_bounds__(256) void k_norm(unsigned* __restrict__ ec,
                                              const int* __restrict__ rowptr,
                                              const float* __restrict__ dinv, int n){
  int node = blockIdx.x*4 + (threadIdx.x >> 6);
  if (node >= n) return;
  int lane = threadIdx.x & 63;
  int e0 = rowptr[node], e1 = rowptr[node+1];
  float dr = dinv[node];
  for (int e = e0 + lane; e < e1; e += 64){
    unsigned u = ec[e];
    int c = u & 0x1FFFF;
    float wn = dr * edgeWpos(u) * dinv[c];
    ec[e] = packEdge(c, wn);
  }
}

__global__ void k_transw_all(const float* __restrict__ W1, const float* __restrict__ c1W,
                             const float* __restrict__ c2W, bf16_t* __restrict__ Wt1,
                             bf16_t* __restrict__ Wtc1, bf16_t* __restrict__ Wtc2){
  int idx = blockIdx.x*256 + threadIdx.x;   // 8*16384 total
  const float* src; bf16_t* dst; int local;
  if (idx < 2*16384)      { src = W1;  dst = Wt1;  local = idx; }
  else if (idx < 5*16384) { src = c1W; dst = Wtc1; local = idx - 2*16384; }
  else                    { src = c2W; dst = Wtc2; local = idx - 5*16384; }
  int c = local >> 14, r = (local >> 7) & 127, j = local & 127;
  dst[(c << 14) + (j << 7) + r] = (bf16_t)src[local];
}

// ---------------- GEMM1: A = relu(x @ W1 + b1), x f32 row-major K=256, out row-major ----
__global__ __launch_bounds__(256) void k_gemm1(
    const float* __restrict__ x, const bf16_t* __restrict__ Wt, const float* __restrict__ bias,
    bf16_t* __restrict__ out, int M)
{
  __shared__ bf16_t As[128][40];
  const int tid = threadIdx.x;
  const int wave = tid >> 6, lane = tid & 63;
  const int wm = wave >> 1, wn = wave & 1;
  const int l15 = lane & 15, lq = lane >> 4;
  const int blockRow = blockIdx.x * 128;

  f32x4 acc[4][4];
  #pragma unroll
  for (int a = 0; a < 4; ++a)
    #pragma unroll
    for (int b = 0; b < 4; ++b) acc[a][b] = f32x4{0.f,0.f,0.f,0.f};

  const int srow = tid >> 1;
  const int scol = (tid & 1) * 16;
  const int grow = blockRow + srow;

  #pragma unroll
  for (int chunk = 0; chunk < 2; ++chunk){
    #pragma unroll
    for (int k4 = 0; k4 < 4; ++k4){
      const int kk = k4 * 32;
      {
        union { bf16_t h[16]; uint4 q[2]; } u;
        if (grow < M){
          const float* p = x + (size_t)grow*256 + chunk*128 + kk + scol;
          floatv4 vv[4];
          #pragma unroll
          for (int j = 0; j < 4; ++j) vv[j] = *(const floatv4*)(p + j*4);
          #pragma unroll
          for (int j = 0; j < 16; ++j) u.h[j] = (bf16_t)vv[j>>2][j&3];
        } else {
          u.q[0] = make_uint4(0,0,0,0);
          u.q[1] = make_uint4(0,0,0,0);
        }
        *(uint4*)&As[srow][scol]     = u.q[0];
        *(uint4*)&As[srow][scol + 8] = u.q[1];
      }
      __syncthreads();
      bf16x8 af[4], bfr[4];
      #pragma unroll
      for (int fm = 0; fm < 4; ++fm)
        af[fm] = *(const bf16x8*)&As[wm*64 + fm*16 + l15][lq*8];
      #pragma unroll
      for (int fn = 0; fn < 4; ++fn){
        int colg = wn*64 + fn*16 + l15;
        bfr[fn] = *(const bf16x8*)&Wt[((size_t)((chunk << 7) + colg) << 7) + kk + lq*8];
      }
      #pragma unroll
      for (int fm = 0; fm < 4; ++fm)
        #pragma unroll
        for (int fn = 0; fn < 4; ++fn)
          acc[fm][fn] = __builtin_amdgcn_mfma_f32_16x16x32_bf16(af[fm], bfr[fn], acc[fm][fn], 0, 0, 0);
      __syncthreads();
    }
  }
  #pragma unroll
  for (int fm = 0; fm < 4; ++fm){
    #pragma unroll
    for (int j = 0; j < 4; ++j){
      int growo = blockRow + wm*64 + fm*16 + lq*4 + j;
      if (growo < M){
        #pragma unroll
        for (int fn = 0; fn < 4; ++fn){
          int c = wn*64 + fn*16 + l15;
          float v = fmaxf(acc[fm][fn][j] + bias[c], 0.f);
          out[((size_t)growo << 7) + c] = (bf16_t)v;
        }
      }
    }
  }
}

// ---------------- conv GEMM, barrier-free, row-major in/out ----------------
__global__ __launch_bounds__(256) void k_gemm_nb(
    const bf16_t* __restrict__ a0, const bf16_t* __restrict__ a1, const bf16_t* __restrict__ a2,
    const bf16_t* __restrict__ Wt, const float* __restrict__ bias,
    bf16_t* __restrict__ out, int M)
{
  const int tid = threadIdx.x;
  const int wave = tid >> 6, lane = tid & 63;
  const int wm = wave >> 1, wn = wave & 1;
  const int l15 = lane & 15, lq = lane >> 4;
  const int blockRow = blockIdx.x * 128;
  const int arow = blockRow + wm*64 + l15;   // + fm*16
  // last block reads A rows [100000,100096): spills into the adjacent ws buffer
  // (allocated, value-irrelevant — those acc rows are never stored).

  f32x4 acc[4][4];
  #pragma unroll
  for (int a = 0; a < 4; ++a)
    #pragma unroll
    for (int b = 0; b < 4; ++b) acc[a][b] = f32x4{0.f,0.f,0.f,0.f};

  #pragma unroll
  for (int chunk = 0; chunk < 3; ++chunk){
    const bf16_t* src = (chunk == 0) ? a0 : ((chunk == 1) ? a1 : a2);
    #pragma unroll
    for (int k4 = 0; k4 < 4; ++k4){
      const int kk = k4*32 + lq*8;
      bf16x8 af[4], bfr[4];
      #pragma unroll
      for (int fm = 0; fm < 4; ++fm)
        af[fm] = *(const bf16x8*)(src + (((size_t)(arow + fm*16)) << 7) + kk);
      #pragma unroll
      for (int fn = 0; fn < 4; ++fn)
        bfr[fn] = *(const bf16x8*)(Wt + ((size_t)((chunk << 7) + wn*64 + fn*16 + l15) << 7) + kk);
      #pragma unroll
      for (int fm = 0; fm < 4; ++fm)
        #pragma unroll
        for (int fn = 0; fn < 4; ++fn)
          acc[fm][fn] = __builtin_amdgcn_mfma_f32_16x16x32_bf16(af[fm], bfr[fn], acc[fm][fn], 0, 0, 0);
    }
  }
  #pragma unroll
  for (int fm = 0; fm < 4; ++fm){
    #pragma unroll
    for (int j = 0; j < 4; ++j){
      int growo = blockRow + wm*64 + fm*16 + lq*4 + j;
      if (growo < M){
        #pragma unroll
        for (int fn = 0; fn < 4; ++fn){
          int c = wn*64 + fn*16 + l15;
          float v = fmaxf(acc[fm][fn][j] + bias[c], 0.f);
          out[((size_t)growo << 7) + c] = (bf16_t)v;
        }
      }
    }
  }
}

// ---------------- SpMM: 4 nodes/wave, 16 lanes/node, 16B/lane gathers, packed edges ----
static __device__ __forceinline__ void accum8(float* a, uint4 p, float w){
  a[0] += w*bflo(p.x); a[1] += w*bfhi(p.x);
  a[2] += w*bflo(p.y); a[3] += w*bfhi(p.y);
  a[4] += w*bflo(p.z); a[5] += w*bfhi(p.z);
  a[6] += w*bflo(p.w); a[7] += w*bfhi(p.w);
}

__global__ __launch_bounds__(256) void k_spmm4(
    const int* __restrict__ rowptr, const unsigned* __restrict__ ec,
    const bf16_t* __restrict__ V, const bf16_t* __restrict__ sub, float alpha,
    bf16_t* __restrict__ out, int n)
{
  const int lane = threadIdx.x & 63;
  const int wave = threadIdx.x >> 6;
  const int g = lane >> 4;
  const int s = lane & 15;
  const int node = blockIdx.x*16 + wave*4 + g;
  if (node >= n) return;

  int e = rowptr[node];
  const int e1 = rowptr[node+1];
  const char* Vb = (const char*)V;
  const int fb = s << 4;

  float acc[8] = {0.f,0.f,0.f,0.f,0.f,0.f,0.f,0.f};

  for (; e + 4 <= e1; e += 4){
    unsigned u0 = ec[e], u1 = ec[e+1], u2 = ec[e+2], u3 = ec[e+3];
    uint4 p0 = *(const uint4*)(Vb + (((size_t)(u0 & 0x1FFFF)) << 8) + fb);
    uint4 p1 = *(const uint4*)(Vb + (((size_t)(u1 & 0x1FFFF)) << 8) + fb);
    uint4 p2 = *(const uint4*)(Vb + (((size_t)(u2 & 0x1FFFF)) << 8) + fb);
    uint4 p3 = *(const uint4*)(Vb + (((size_t)(u3 & 0x1FFFF)) << 8) + fb);
    accum8(acc, p0, edgeWneg(u0));
    accum8(acc, p1, edgeWneg(u1));
    accum8(acc, p2, edgeWneg(u2));
    accum8(acc, p3, edgeWneg(u3));
  }
  for (; e < e1; ++e){
    unsigned u = ec[e];
    uint4 p = *(const uint4*)(Vb + (((size_t)(u & 0x1FFFF)) << 8) + fb);
    accum8(acc, p, edgeWneg(u));
  }

  uint4 o;
  if (sub){
    uint4 sv = *(const uint4*)((const char*)sub + (((size_t)node) << 8) + fb);
    o.x = pack2(alpha*acc[0] - bflo(sv.x), alpha*acc[1] - bfhi(sv.x));
    o.y = pack2(alpha*acc[2] - bflo(sv.y), alpha*acc[3] - bfhi(sv.y));
    o.z = pack2(alpha*acc[4] - bflo(sv.z), alpha*acc[5] - bfhi(sv.z));
    o.w = pack2(alpha*acc[6] - bflo(sv.w), alpha*acc[7] - bfhi(sv.w));
  } else {
    o.x = pack2(alpha*acc[0], alpha*acc[1]);
    o.y = pack2(alpha*acc[2], alpha*acc[3]);
    o.z = pack2(alpha*acc[4], alpha*acc[5]);
    o.w = pack2(alpha*acc[6], alpha*acc[7]);
  }
  *(uint4*)((char*)out + (((size_t)node) << 8) + fb) = o;
}

// ---------------- head ----------------
__global__ __launch_bounds__(256) void k_head(
    const bf16_t* __restrict__ h, const float* __restrict__ W2, const float* __restrict__ b2,
    float* __restrict__ out, int n)
{
  int node = blockIdx.x*4 + (threadIdx.x >> 6);
  if (node >= n) return;
  int lane = threadIdx.x & 63;
  unsigned int p = *(const unsigned int*)(h + ((size_t)node << 7) + lane*2);
  float h0 = bflo(p), h1 = bfhi(p);
  floatv4 w = *(const floatv4*)(W2 + lane*4);
  float p0 = h0*w[0] + h1*w[2];
  float p1 = h0*w[1] + h1*w[3];
  #pragma unroll
  for (int s = 32; s > 0; s >>= 1){
    p0 += __shfl_xor(p0, s, 64);
    p1 += __shfl_xor(p1, s, 64);
  }
  if (lane == 0){
    float l0 = p0 + b2[0], l1 = p1 + b2[1];
    float m = fmaxf(l0, l1);
    float e0 = __expf(l0 - m), e1 = __expf(l1 - m);
    float inv = 1.f / (e0 + e1);
    out[(size_t)node*2]     = e0 * inv;
    out[(size_t)node*2 + 1] = e1 * inv;
  }
}

// ---------------- launch ----------------

extern "C" void kernel_launch(void* const* d_in, const int* in_sizes, int n_in,
                              void* d_out, int out_size, void* d_ws, size_t ws_size,
                              hipStream_t stream)
{
  const float* x   = (const float*)d_in[0];
  const int*   ei  = (const int*)d_in[1];
  const float* ew  = (const float*)d_in[2];
  const float* W1  = (const float*)d_in[3];
  const float* b1  = (const float*)d_in[4];
  const float* c1W = (const float*)d_in[5];
  const float* c1b = (const float*)d_in[6];
  const float* c2W = (const float*)d_in[7];
  const float* c2b = (const float*)d_in[8];
  const float* W2  = (const float*)d_in[9];
  const float* b2  = (const float*)d_in[10];
  float* out = (float*)d_out;

  const int n = NN, e = NE;
  const int* row = ei;
  const int* col = ei + e;

  char* ws = (char*)d_ws;
  size_t off = 0;
  auto carve = [&](size_t bytes)->void*{
    void* p = ws + off;
    off += (bytes + 255) & ~(size_t)255;
    return p;
  };
  bf16_t* A    = (bf16_t*)carve((size_t)n*128*2);
  bf16_t* B    = (bf16_t*)carve((size_t)n*128*2);
  bf16_t* C    = (bf16_t*)carve((size_t)n*128*2);
  bf16_t* D    = (bf16_t*)carve((size_t)n*128*2);
  float*  dinv = (float*)carve((size_t)n*4);
  int*    rowptr = (int*)carve((size_t)(n+1)*4);
  unsigned* ec = (unsigned*)carve((size_t)e*4);
  int*    bincnt = (int*)carve((size_t)NBIN*4);
  int*    binptr = (int*)carve((size_t)(NBIN+1)*4);
  int*    blockbase = (int*)carve((size_t)NBB*NBIN*4);   // 1.22MB
  bf16_t* Wt1  = (bf16_t*)carve(2*128*128*2);
  bf16_t* Wtc1 = (bf16_t*)carve(3*128*128*2);
  bf16_t* Wtc2 = (bf16_t*)carve(3*128*128*2);
  // temp edge buffer (12.8MB) aliases D: binB writes it, binC consumes it,
  // and D is first written much later (conv1 k_gemm_nb).
  int2* temp = (int2*)D;
  (void)ws_size; (void)in_sizes; (void)n_in; (void)out_size;

  const int NB_W = (n + 3)/4;       // 25000
  const int NB_S = (n + 15)/16;     // 6250

  hipMemsetAsync(bincnt, 0, (size_t)NBIN*4, stream);
  k_binA<<<NBB,256,0,stream>>>(row, bincnt, blockbase);
  k_scanbins<<<1,256,0,stream>>>(bincnt, binptr, rowptr);
  k_binB<<<NBB,256,0,stream>>>(row, col, ew, binptr, blockbase, temp);
  k_binC<<<NBIN,256,0,stream>>>(temp, binptr, ec, rowptr, dinv, n);
  k_norm<<<NB_W,256,0,stream>>>(ec, rowptr, dinv, n);
  k_transw_all<<<(8*16384+255)/256,256,0,stream>>>(W1, c1W, c2W, Wt1, Wtc1, Wtc2);

  // h0 = relu(x @ W1 + b1) -> A
  k_gemm1<<<NB_G,256,0,stream>>>(x, Wt1, b1, A, n);
  // conv1: Tx1 = Lx(h0) -> B ; Tx2 = 2*Lx(Tx1) - h0 -> C
  k_spmm4<<<NB_S,256,0,stream>>>(rowptr, ec, A, nullptr, 1.f, B, n);
  k_spmm4<<<NB_S,256,0,stream>>>(rowptr, ec, B, A, 2.f, C, n);
  k_gemm_nb<<<NB_G,256,0,stream>>>(A, B, C, Wtc1, c1b, D, n);
  // conv2
  k_spmm4<<<NB_S,256,0,stream>>>(rowptr, ec, D, nullptr, 1.f, B, n);
  k_spmm4<<<NB_S,256,0,stream>>>(rowptr, ec, B, D, 2.f, C, n);
  k_gemm_nb<<<NB_G,256,0,stream>>>(D, B, C, Wtc2, c2b, A, n);
  // head
  k_head<<<NB_W,256,0,stream>>>(A, W2, b2, out, n);
}